// Round 8
// baseline (855.686 us; speedup 1.0000x reference)
//
#include <hip/hip_runtime.h>

#define HID 2048
#define NH 16
#define DH 128
#define DFF 8192
#define BB 2
#define TT 2048
#define MROWS 4096   // B*T

typedef __bf16 bf16x8 __attribute__((ext_vector_type(8)));
typedef __bf16 bf16x4 __attribute__((ext_vector_type(4)));
typedef float  f32x4  __attribute__((ext_vector_type(4)));

__device__ __forceinline__ f32x4 mfma16(bf16x8 a, bf16x8 b, f32x4 c) {
    return __builtin_amdgcn_mfma_f32_16x16x32_bf16(a, b, c, 0, 0, 0);
}

__device__ __forceinline__ void gload_lds16(const __bf16* gsrc, __bf16* ldst) {
    __builtin_amdgcn_global_load_lds(
        (const __attribute__((address_space(1))) void*)gsrc,
        (__attribute__((address_space(3))) void*)ldst, 16, 0, 0);
}

// ---------------- weight transpose+convert: W[K][N] f32 -> Wt[N][K] bf16 ----
// float4 loads (1 KB/wave-instr), bf16x4 stores (512 B/wave-instr).
template<int K, int N>
__global__ __launch_bounds__(256) void transpose_bf16_kernel(
    const float* __restrict__ W, __bf16* __restrict__ Wt) {
    __shared__ float tile[64][65];
    int t = threadIdx.x;
    int n0 = blockIdx.x * 64, k0 = blockIdx.y * 64;
    int n4 = (t & 15) * 4, kk = t >> 4;
    #pragma unroll
    for (int i = 0; i < 4; i++) {
        int k = i * 16 + kk;
        float4 v = *(const float4*)(W + (size_t)(k0 + k) * N + n0 + n4);
        tile[k][n4] = v.x; tile[k][n4 + 1] = v.y;
        tile[k][n4 + 2] = v.z; tile[k][n4 + 3] = v.w;
    }
    __syncthreads();
    int k4 = (t & 15) * 4, nn = t >> 4;
    #pragma unroll
    for (int i = 0; i < 4; i++) {
        int n = i * 16 + nn;
        bf16x4 o;
        #pragma unroll
        for (int j = 0; j < 4; j++) o[j] = (__bf16)tile[k4 + j][n];
        *(bf16x4*)(Wt + (size_t)(n0 + n) * K + k0 + k4) = o;
    }
}

// ---------------- LayerNorm f32 -> bf16 ------------------------------------
__global__ __launch_bounds__(256) void ln_kernel(
    const float* __restrict__ x, const float* __restrict__ gw,
    const float* __restrict__ gb, __bf16* __restrict__ out) {
    int row = blockIdx.x;
    int t = threadIdx.x;
    const float* xr = x + (size_t)row * HID;
    float4 v0 = *(const float4*)(xr + t * 8);
    float4 v1 = *(const float4*)(xr + t * 8 + 4);
    float xv[8] = {v0.x, v0.y, v0.z, v0.w, v1.x, v1.y, v1.z, v1.w};
    float s = 0.f, q = 0.f;
    #pragma unroll
    for (int j = 0; j < 8; j++) { s += xv[j]; q += xv[j] * xv[j]; }
    #pragma unroll
    for (int off = 1; off < 64; off <<= 1) {
        s += __shfl_xor(s, off);
        q += __shfl_xor(q, off);
    }
    __shared__ float ssum[4], ssq[4];
    if ((t & 63) == 0) { ssum[t >> 6] = s; ssq[t >> 6] = q; }
    __syncthreads();
    s = ssum[0] + ssum[1] + ssum[2] + ssum[3];
    q = ssq[0] + ssq[1] + ssq[2] + ssq[3];
    float mu = s * (1.0f / HID);
    float var = q * (1.0f / HID) - mu * mu;
    float rs = rsqrtf(var + 1e-5f);
    bf16x8 o;
    #pragma unroll
    for (int j = 0; j < 8; j++)
        o[j] = (__bf16)((xv[j] - mu) * rs * gw[t * 8 + j] + gb[t * 8 + j]);
    *(bf16x8*)(out + (size_t)row * HID + t * 8) = o;
}

// ---------------- init kernels for K-split atomic GEMMs ---------------------
template<int HB>
__global__ __launch_bounds__(256) void init_resid_kernel(
    const float* __restrict__ src, const float* __restrict__ bias,
    float* __restrict__ out) {
    int i = blockIdx.x * 256 + threadIdx.x;
    float4 a = ((const float4*)src)[i];
    if constexpr (HB) {
        float4 bb = ((const float4*)bias)[i & (HID / 4 - 1)];
        a.x += bb.x; a.y += bb.y; a.z += bb.z; a.w += bb.w;
    }
    ((float4*)out)[i] = a;
}

// ---------------- 128x128 m97-structure GEMM (multi-block occupancy) --------
// 4 waves / 256 thr, BK=64, 32 KB LDS single-buffered, 2-barrier loop.
// Relies on 3-4 co-resident blocks/CU for cross-block barrier hiding (m97/m114)
// instead of in-block pipelining. Conflict-free 8-row XOR swizzle (both sides).
// EPI: 2=f32 +resid, 3=bf16 silu(+bias), 5=f32 atomicAdd (K-split),
//      6=QKV split (C0=q bf16, C1=k bf16, C2=v transposed [B,NH,DH,T])
template<int EPI, int KSPLIT, int N, int K>
__global__ __launch_bounds__(256) void gemm128(
    const __bf16* __restrict__ A, const __bf16* __restrict__ Bt,
    void* __restrict__ C0, void* __restrict__ C1, void* __restrict__ C2,
    const float* __restrict__ resid, const float* __restrict__ bias, int nN) {
    constexpr int BK = 64;
    constexpr int KS = K / KSPLIT;
    constexpr int NT = KS / BK;

    __shared__ __align__(16) __bf16 As[128 * BK];   // 16 KB
    __shared__ __align__(16) __bf16 Bs[128 * BK];   // 16 KB

    int tid = threadIdx.x;
    int w = tid >> 6, l = tid & 63;
    int wr = w >> 1, wc = w & 1;
    int qi = l & 15, g = l >> 4;

    int nwg = gridDim.x, bid = blockIdx.x;
    int wg = (bid & 7) * (nwg >> 3) + (bid >> 3);   // XCD swizzle (nwg%8==0)
    int nMN = nwg / KSPLIT;
    int tileid = wg % nMN, kh = wg / nMN;
    int bm = tileid / nN, bn = tileid % nN;
    int row0 = bm * 128, col0 = bn * 128, kb0 = kh * KS;

    // staging: 4 slots/thread per matrix; slot = i*256+tid -> row r, chunk u8.
    // Source chunk pre-swizzled (u8 ^ (r&7)) so LDS stays linear (rule #21).
    const __bf16 *pA[4], *pB[4];
    __bf16 *dA[4], *dB[4];
    #pragma unroll
    for (int i = 0; i < 4; i++) {
        int slot = i * 256 + tid;
        int r = slot >> 3, u8 = slot & 7;
        pA[i] = A + (size_t)(row0 + r) * K + kb0 + (u8 ^ (r & 7)) * 8;
        pB[i] = Bt + (size_t)(col0 + r) * K + kb0 + (u8 ^ (r & 7)) * 8;
        dA[i] = As + (i * 256 + w * 64) * 8;    // wave-uniform dest base
        dB[i] = Bs + (i * 256 + w * 64) * 8;
    }

    // fragment read bases: row r has r&7 == qi&7 -> swizzle folds to xk0/xk1
    int xk0 = (g * 16) ^ ((qi & 7) << 4);
    int xk1 = (64 + g * 16) ^ ((qi & 7) << 4);
    const char* arow = (const char*)As + (wr * 64 + qi) * 128;
    const char* brow = (const char*)Bs + (wc * 64 + qi) * 128;

    f32x4 acc[4][4] = {};

    for (int t = 0; t < NT; t++) {
        __syncthreads();                         // readers of tile t-1 done
        #pragma unroll
        for (int i = 0; i < 4; i++) gload_lds16(pA[i] + t * BK, dA[i]);
        #pragma unroll
        for (int i = 0; i < 4; i++) gload_lds16(pB[i] + t * BK, dB[i]);
        __syncthreads();                         // vmcnt(0) drain + barrier

        bf16x8 aF[4][2], bF[4][2];
        #pragma unroll
        for (int m = 0; m < 4; m++) {
            aF[m][0] = *(const bf16x8*)(arow + m * 2048 + xk0);
            aF[m][1] = *(const bf16x8*)(arow + m * 2048 + xk1);
        }
        #pragma unroll
        for (int n = 0; n < 4; n++) {
            bF[n][0] = *(const bf16x8*)(brow + n * 2048 + xk0);
            bF[n][1] = *(const bf16x8*)(brow + n * 2048 + xk1);
        }
        #pragma unroll
        for (int kk = 0; kk < 2; kk++)
            #pragma unroll
            for (int m = 0; m < 4; m++)
                #pragma unroll
                for (int n = 0; n < 4; n++)
                    acc[m][n] = mfma16(aF[m][kk], bF[n][kk], acc[m][n]);
    }

    // epilogue: D layout col=lane&15, row=(lane>>4)*4+r
    #pragma unroll
    for (int m = 0; m < 4; m++) {
        int Rb = row0 + wr * 64 + m * 16 + g * 4;
        #pragma unroll
        for (int n = 0; n < 4; n++) {
            int C = col0 + wc * 64 + n * 16 + qi;
            f32x4 v = acc[m][n];
            if constexpr (EPI == 6) {
                int region = C >> 11;            // uniform per block (BN=128)
                int Cl = C & 2047;
                if (region < 2) {
                    __bf16* dst = (__bf16*)(region == 0 ? C0 : C1);
                    #pragma unroll
                    for (int r = 0; r < 4; r++)
                        dst[(size_t)(Rb + r) * 2048 + Cl] = (__bf16)v[r];
                } else {
                    bf16x4 pk;
                    #pragma unroll
                    for (int r = 0; r < 4; r++) pk[r] = (__bf16)v[r];
                    int b = Rb >> 11, t0 = Rb & 2047, hh = Cl >> 7, d = Cl & 127;
                    *(bf16x4*)((__bf16*)C2 +
                        ((size_t)(b * NH + hh) * DH + d) * TT + t0) = pk;
                }
            } else {
                #pragma unroll
                for (int r = 0; r < 4; r++) {
                    size_t idx = (size_t)(Rb + r) * N + C;
                    if constexpr (EPI == 2) {
                        ((float*)C0)[idx] = resid[idx] + v[r];
                    } else if constexpr (EPI == 3) {
                        float u = v[r] + bias[C];
                        ((__bf16*)C0)[idx] = (__bf16)(u / (1.f + __expf(-u)));
                    } else if constexpr (EPI == 5) {
                        atomicAdd((float*)C0 + idx, v[r]);
                    }
                }
            }
        }
    }
}

// ---------------- flash attention, KVBLK=64 LDS-staged + XOR swizzle --------
__global__ __launch_bounds__(256) void attn_kernel(
    const __bf16* __restrict__ qh, const __bf16* __restrict__ kh,
    const __bf16* __restrict__ vt, __bf16* __restrict__ out) {
    __shared__ __align__(16) __bf16 Ks[64 * 128];
    __shared__ __align__(16) __bf16 Vts[128 * 64];
    __shared__ __align__(16) __bf16 plds[4][1024];
    int tid = threadIdx.x;
    int w = tid >> 6, l = tid & 63;
    int qi = l & 15, g = l >> 4;
    int bh = blockIdx.y;
    int b = bh >> 4, hd = bh & 15;
    int qtile = gridDim.x - 1 - blockIdx.x;
    int qbase = qtile * 64 + w * 16;
    int qg = qbase + qi;

    const __bf16* qrow = qh + ((size_t)b * TT + qg) * HID + hd * DH;
    const __bf16* kbase = kh + (size_t)b * TT * HID + hd * DH;
    const __bf16* vtb = vt + (size_t)bh * DH * TT;

    bf16x8 bq[4];
    #pragma unroll
    for (int kc = 0; kc < 4; kc++)
        bq[kc] = *(const bf16x8*)(qrow + kc * 32 + g * 8);

    f32x4 O[8] = {};
    float m_run = -3.0e38f, l_run = 0.f;
    const float scale = 0.08838834764831845f;
    int nt = qtile + 1;

    for (int it = 0; it < nt; it++) {
        int kv0 = it * 64;
        __syncthreads();
        #pragma unroll
        for (int i = 0; i < 4; i++) {
            int j = (w * 4 + i) * 64 + l;
            int r = j >> 4, u = j & 15;
            int cb = (u * 16) ^ ((r & 7) << 4);
            gload_lds16(kbase + (size_t)(kv0 + r) * HID + (cb >> 1),
                        Ks + (w * 4 + i) * 512);
        }
        #pragma unroll
        for (int i = 0; i < 4; i++) {
            int j = (w * 4 + i) * 64 + l;
            int r = j >> 3, u = j & 7;
            int cb = (u * 16) ^ ((r & 7) << 4);
            gload_lds16(vtb + (size_t)r * TT + kv0 + (cb >> 1),
                        Vts + (w * 4 + i) * 512);
        }
        __syncthreads();

        f32x4 st[4] = {};
        #pragma unroll
        for (int t = 0; t < 4; t++) {
            #pragma unroll
            for (int kc = 0; kc < 4; kc++) {
                int row = t * 16 + qi;
                int cb = (kc * 64 + g * 16) ^ ((qi & 7) << 4);
                bf16x8 ak = *(const bf16x8*)(Ks + row * 128 + (cb >> 1));
                st[t] = mfma16(ak, bq[kc], st[t]);
            }
        }
        float s[16];
        #pragma unroll
        for (int t = 0; t < 4; t++)
            #pragma unroll
            for (int r = 0; r < 4; r++) s[t * 4 + r] = st[t][r] * scale;
        #pragma unroll
        for (int i = 0; i < 16; i++) {
            int kvg = kv0 + (i >> 2) * 16 + g * 4 + (i & 3);
            if (kvg > qg) s[i] = -3.0e38f;
        }
        float mt = s[0];
        #pragma unroll
        for (int i = 1; i < 16; i++) mt = fmaxf(mt, s[i]);
        mt = fmaxf(mt, __shfl_xor(mt, 16));
        mt = fmaxf(mt, __shfl_xor(mt, 32));
        float m_new = fmaxf(m_run, mt);
        float alpha = __expf(m_run - m_new);
        float p[16], ps = 0.f;
        #pragma unroll
        for (int i = 0; i < 16; i++) { p[i] = __expf(s[i] - m_new); ps += p[i]; }
        ps += __shfl_xor(ps, 16);
        ps += __shfl_xor(ps, 32);
        l_run = l_run * alpha + ps;
        m_run = m_new;

        #pragma unroll
        for (int t = 0; t < 4; t++) {
            bf16x4 pk;
            #pragma unroll
            for (int r = 0; r < 4; r++) pk[r] = (__bf16)p[t * 4 + r];
            int cb = (t * 32 + g * 8) ^ ((qi & 7) << 4);
            *(bf16x4*)(&plds[w][qi * 64 + (cb >> 1)]) = pk;
        }

        float av[4];
        #pragma unroll
        for (int r = 0; r < 4; r++) av[r] = __shfl(alpha, (g << 4) | (g * 4 + r));
        #pragma unroll
        for (int oc = 0; oc < 8; oc++)
            #pragma unroll
            for (int r = 0; r < 4; r++) O[oc][r] *= av[r];

        #pragma unroll
        for (int h = 0; h < 2; h++) {
            int cbp = (h * 64 + g * 16) ^ ((qi & 7) << 4);
            bf16x8 ap = *(const bf16x8*)(&plds[w][qi * 64 + (cbp >> 1)]);
            #pragma unroll
            for (int oc = 0; oc < 8; oc++) {
                int row = oc * 16 + qi;
                int cb = (h * 64 + g * 16) ^ ((qi & 7) << 4);
                bf16x8 bv = *(const bf16x8*)(Vts + row * 64 + (cb >> 1));
                O[oc] = mfma16(ap, bv, O[oc]);
            }
        }
    }

    float linv[4];
    #pragma unroll
    for (int r = 0; r < 4; r++) {
        float lq = __shfl(l_run, (g << 4) | (g * 4 + r));
        linv[r] = 1.0f / lq;
    }
    __bf16* op = out + ((size_t)b * TT + qbase) * HID + hd * DH;
    #pragma unroll
    for (int oc = 0; oc < 8; oc++)
        #pragma unroll
        for (int r = 0; r < 4; r++)
            op[(size_t)(g * 4 + r) * HID + oc * 16 + qi] = (__bf16)(O[oc][r] * linv[r]);
}

// ---------------- launch ----------------------------------------------------
extern "C" void kernel_launch(void* const* d_in, const int* in_sizes, int n_in,
                              void* d_out, int out_size, void* d_ws, size_t ws_size,
                              hipStream_t stream) {
    const float* x    = (const float*)d_in[0];
    const float* Wq   = (const float*)d_in[2];
    const float* Wk   = (const float*)d_in[3];
    const float* Wv   = (const float*)d_in[4];
    const float* Wo   = (const float*)d_in[5];
    const float* ln1w = (const float*)d_in[6];
    const float* ln1b = (const float*)d_in[7];
    const float* ln2w = (const float*)d_in[8];
    const float* ln2b = (const float*)d_in[9];
    const float* W1   = (const float*)d_in[10];
    const float* b1   = (const float*)d_in[11];
    const float* W2   = (const float*)d_in[12];
    const float* b2   = (const float*)d_in[13];
    float* outp = (float*)d_out;

    char* ws = (char*)d_ws;
    const size_t SZ_W   = (size_t)HID * HID * 2;
    const size_t SZ_WF  = (size_t)HID * DFF * 2;
    const size_t SZ_ACT = (size_t)MROWS * HID * 2;
    const size_t SZ_X32 = (size_t)MROWS * HID * 4;

    __bf16* wqT  = (__bf16*)(ws);                   // wq|wk|wv contiguous
    __bf16* wkT  = (__bf16*)(ws + SZ_W);
    __bf16* wvT  = (__bf16*)(ws + 2 * SZ_W);
    __bf16* woT  = (__bf16*)(ws + 3 * SZ_W);
    __bf16* w1T  = (__bf16*)(ws + 4 * SZ_W);
    __bf16* w2T  = (__bf16*)(ws + 4 * SZ_W + SZ_WF);
    __bf16* h    = (__bf16*)(ws + 4 * SZ_W + 2 * SZ_WF);
    float*  x1   = (float*) (ws + 4 * SZ_W + 2 * SZ_WF + SZ_ACT);
    char*   base = ws + 4 * SZ_W + 2 * SZ_WF + SZ_ACT + SZ_X32;
    __bf16* qb   = (__bf16*)(base);
    __bf16* kb   = (__bf16*)(base + SZ_ACT);
    __bf16* vtb  = (__bf16*)(base + 2 * SZ_ACT);
    __bf16* attn = (__bf16*)(base + 3 * SZ_ACT);
    __bf16* mlp1 = (__bf16*)(base);                  // aliases q/k/vt/attn

    dim3 blk256(256);
    transpose_bf16_kernel<HID, HID><<<dim3(32, 32), blk256, 0, stream>>>(Wq, wqT);
    transpose_bf16_kernel<HID, HID><<<dim3(32, 32), blk256, 0, stream>>>(Wk, wkT);
    transpose_bf16_kernel<HID, HID><<<dim3(32, 32), blk256, 0, stream>>>(Wv, wvT);
    transpose_bf16_kernel<HID, HID><<<dim3(32, 32), blk256, 0, stream>>>(Wo, woT);
    transpose_bf16_kernel<HID, DFF><<<dim3(128, 32), blk256, 0, stream>>>(W1, w1T);
    transpose_bf16_kernel<DFF, HID><<<dim3(32, 128), blk256, 0, stream>>>(W2, w2T);

    ln_kernel<<<MROWS, blk256, 0, stream>>>(x, ln1w, ln1b, h);

    // fused QKV: 32x48 = 1536 blocks (6 blocks/CU)
    gemm128<6, 1, 6144, HID><<<1536, blk256, 0, stream>>>(
        h, wqT, qb, kb, vtb, nullptr, nullptr, 48);

    attn_kernel<<<dim3(TT / 64, BB * NH), blk256, 0, stream>>>(qb, kb, vtb, attn);

    // O projection + residual: init x1 = x, then 2-way K-split (1024 blocks)
    init_resid_kernel<0><<<MROWS * HID / 4 / 256, blk256, 0, stream>>>(x, nullptr, x1);
    gemm128<5, 2, HID, HID><<<1024, blk256, 0, stream>>>(
        attn, woT, x1, nullptr, nullptr, nullptr, nullptr, 16);

    ln_kernel<<<MROWS, blk256, 0, stream>>>(x1, ln2w, ln2b, h);

    // MLP1: 32x64 = 2048 blocks (8 blocks/CU)
    gemm128<3, 1, DFF, HID><<<2048, blk256, 0, stream>>>(
        h, w1T, mlp1, nullptr, nullptr, nullptr, b1, 64);

    // MLP2: init out = x1 + b2, then 2-way K-split (1024 blocks)
    init_resid_kernel<1><<<MROWS * HID / 4 / 256, blk256, 0, stream>>>(x1, b2, outp);
    gemm128<5, 2, HID, DFF><<<1024, blk256, 0, stream>>>(
        mlp1, w2T, outp, nullptr, nullptr, nullptr, nullptr, 16);
}

// Round 9
// 787.985 us; speedup vs baseline: 1.0859x; 1.0859x over previous
//
#include <hip/hip_runtime.h>

#define HID 2048
#define NH 16
#define DH 128
#define DFF 8192
#define BB 2
#define TT 2048
#define MROWS 4096   // B*T

typedef __bf16 bf16x8 __attribute__((ext_vector_type(8)));
typedef __bf16 bf16x4 __attribute__((ext_vector_type(4)));
typedef float  f32x4  __attribute__((ext_vector_type(4)));

__device__ __forceinline__ f32x4 mfma16(bf16x8 a, bf16x8 b, f32x4 c) {
    return __builtin_amdgcn_mfma_f32_16x16x32_bf16(a, b, c, 0, 0, 0);
}

__device__ __forceinline__ void gload_lds16(const __bf16* gsrc, __bf16* ldst) {
    __builtin_amdgcn_global_load_lds(
        (const __attribute__((address_space(1))) void*)gsrc,
        (__attribute__((address_space(3))) void*)ldst, 16, 0, 0);
}

// ---------------- weight transpose+convert: W[K][N] f32 -> Wt[N][K] bf16 ----
// float4 loads, bf16x4 stores (vectorized)
template<int K, int N>
__global__ __launch_bounds__(256) void transpose_bf16_kernel(
    const float* __restrict__ W, __bf16* __restrict__ Wt) {
    __shared__ float tile[64][65];
    int t = threadIdx.x;
    int n0 = blockIdx.x * 64, k0 = blockIdx.y * 64;
    int n4 = (t & 15) * 4, kk = t >> 4;
    #pragma unroll
    for (int i = 0; i < 4; i++) {
        int k = i * 16 + kk;
        float4 v = *(const float4*)(W + (size_t)(k0 + k) * N + n0 + n4);
        tile[k][n4] = v.x; tile[k][n4 + 1] = v.y;
        tile[k][n4 + 2] = v.z; tile[k][n4 + 3] = v.w;
    }
    __syncthreads();
    int k4 = (t & 15) * 4, nn = t >> 4;
    #pragma unroll
    for (int i = 0; i < 4; i++) {
        int n = i * 16 + nn;
        bf16x4 o;
        #pragma unroll
        for (int j = 0; j < 4; j++) o[j] = (__bf16)tile[k4 + j][n];
        *(bf16x4*)(Wt + (size_t)(n0 + n) * K + k0 + k4) = o;
    }
}

// ---------------- LayerNorm f32 -> bf16 ------------------------------------
__global__ __launch_bounds__(256) void ln_kernel(
    const float* __restrict__ x, const float* __restrict__ gw,
    const float* __restrict__ gb, __bf16* __restrict__ out) {
    int row = blockIdx.x;
    int t = threadIdx.x;
    const float* xr = x + (size_t)row * HID;
    float4 v0 = *(const float4*)(xr + t * 8);
    float4 v1 = *(const float4*)(xr + t * 8 + 4);
    float xv[8] = {v0.x, v0.y, v0.z, v0.w, v1.x, v1.y, v1.z, v1.w};
    float s = 0.f, q = 0.f;
    #pragma unroll
    for (int j = 0; j < 8; j++) { s += xv[j]; q += xv[j] * xv[j]; }
    #pragma unroll
    for (int off = 1; off < 64; off <<= 1) {
        s += __shfl_xor(s, off);
        q += __shfl_xor(q, off);
    }
    __shared__ float ssum[4], ssq[4];
    if ((t & 63) == 0) { ssum[t >> 6] = s; ssq[t >> 6] = q; }
    __syncthreads();
    s = ssum[0] + ssum[1] + ssum[2] + ssum[3];
    q = ssq[0] + ssq[1] + ssq[2] + ssq[3];
    float mu = s * (1.0f / HID);
    float var = q * (1.0f / HID) - mu * mu;
    float rs = rsqrtf(var + 1e-5f);
    bf16x8 o;
    #pragma unroll
    for (int j = 0; j < 8; j++)
        o[j] = (__bf16)((xv[j] - mu) * rs * gw[t * 8 + j] + gb[t * 8 + j]);
    *(bf16x8*)(out + (size_t)row * HID + t * 8) = o;
}

// ---------------- 8-wave pipelined GEMM (R3 engine, best measured) ----------
// BM=256. 3-deep LDS rotation, counted vmcnt (never 0 mid-loop), 1 barrier
// per K-step, XOR-swizzled LDS (both sides), setprio around MFMA, XCD swizzle.
// All instances BN=128/BK=64 (conflict-free swizzle config).
// EPI: 0=plain bf16, 2=f32 +resid, 3=bf16 silu(+bias), 4=f32 +bias+resid,
//      6=QKV split (C0=q bf16, C1=k bf16, C2=v transposed [B,NH,DH,T])
template<int EPI, int BN, int BK, int N, int K>
__global__ __launch_bounds__(512) void gemm8(
    const __bf16* __restrict__ A, const __bf16* __restrict__ Bt,
    void* __restrict__ C0, void* __restrict__ C1, void* __restrict__ C2,
    const float* __restrict__ resid, const float* __restrict__ bias, int nN) {
    constexpr int BM = 256;
    constexpr int CPR = BK / 8;                 // 16B chunks per LDS row
    constexpr int RND_A = BM * BK * 2 / 8192;   // staging rounds (512thr x 16B)
    constexpr int RND_B = BN * BK * 2 / 8192;
    constexpr int LPT = RND_A + RND_B;          // loads/thread/tile
    constexpr int NT = K / BK;
    constexpr int WC = BN / 4;                  // wave col span
    constexpr int NFRAG = WC / 16;
    constexpr int KK = BK / 32;

    __shared__ __align__(16) __bf16 As[3][BM * BK];
    __shared__ __align__(16) __bf16 Bs[3][BN * BK];

    int tid = threadIdx.x;
    int w = tid >> 6, l = tid & 63;
    int wr = w >> 2, wc = w & 3;
    int qi = l & 15, g = l >> 4;

    int nwg = gridDim.x;
    int bid = blockIdx.x;
    int wg = (bid & 7) * (nwg >> 3) + (bid >> 3);   // XCD swizzle (nwg%8==0)
    int bm = wg / nN, bn = wg % nN;
    int row0 = bm * BM, col0 = bn * BN;

    // per-thread staging source pointers (pre-swizzled chunk, rule #21)
    const __bf16* pA[RND_A];
    #pragma unroll
    for (int i = 0; i < RND_A; i++) {
        int slot = i * 512 + tid;
        int r = slot / CPR, u = slot % CPR;
        pA[i] = A + (size_t)(row0 + r) * K + (u ^ (r & (CPR - 1))) * 8;
    }
    const __bf16* pB[RND_B];
    #pragma unroll
    for (int i = 0; i < RND_B; i++) {
        int slot = i * 512 + tid;
        int r = slot / CPR, u = slot % CPR;
        pB[i] = Bt + (size_t)(col0 + r) * K + (u ^ (r & (CPR - 1))) * 8;
    }
    int wbase = w * 64 * 8;   // wave-uniform LDS dest base (elements)

    f32x4 acc[8][NFRAG] = {};

    // prologue: stage tiles 0,1
    #pragma unroll
    for (int tt = 0; tt < 2; tt++) {
        #pragma unroll
        for (int i = 0; i < RND_A; i++)
            gload_lds16(pA[i] + tt * BK, &As[tt][i * 4096 + wbase]);
        #pragma unroll
        for (int i = 0; i < RND_B; i++)
            gload_lds16(pB[i] + tt * BK, &Bs[tt][i * 4096 + wbase]);
    }

    __bf16 *a0 = As[0], *a1 = As[1], *a2 = As[2];
    __bf16 *b0 = Bs[0], *b1 = Bs[1], *b2 = Bs[2];

    for (int t = 0; t < NT; t++) {
        // tile t landed when <= LPT (tile t+1's loads) outstanding — counted
        if constexpr (LPT == 6) asm volatile("s_waitcnt vmcnt(6)" ::: "memory");
        else                    asm volatile("s_waitcnt vmcnt(4)" ::: "memory");
        __builtin_amdgcn_s_barrier();
        asm volatile("" ::: "memory");
        if (t + 2 < NT) {   // stage tile t+2 into slot that held tile t-1
            #pragma unroll
            for (int i = 0; i < RND_A; i++)
                gload_lds16(pA[i] + (t + 2) * BK, a2 + i * 4096 + wbase);
            #pragma unroll
            for (int i = 0; i < RND_B; i++)
                gload_lds16(pB[i] + (t + 2) * BK, b2 + i * 4096 + wbase);
        }
        bf16x8 af[8][KK], bfr[NFRAG][KK];
        #pragma unroll
        for (int m = 0; m < 8; m++) {
            int r = wr * 128 + m * 16 + qi;
            #pragma unroll
            for (int kk = 0; kk < KK; kk++) {
                int byt = r * (BK * 2) + ((kk * 64 + g * 16) ^ ((r & (CPR - 1)) << 4));
                af[m][kk] = *(const bf16x8*)((const char*)a0 + byt);
            }
        }
        #pragma unroll
        for (int n = 0; n < NFRAG; n++) {
            int r = wc * WC + n * 16 + qi;
            #pragma unroll
            for (int kk = 0; kk < KK; kk++) {
                int byt = r * (BK * 2) + ((kk * 64 + g * 16) ^ ((r & (CPR - 1)) << 4));
                bfr[n][kk] = *(const bf16x8*)((const char*)b0 + byt);
            }
        }
        __builtin_amdgcn_s_setprio(1);
        #pragma unroll
        for (int kk = 0; kk < KK; kk++)
            #pragma unroll
            for (int m = 0; m < 8; m++)
                #pragma unroll
                for (int n = 0; n < NFRAG; n++)
                    acc[m][n] = mfma16(af[m][kk], bfr[n][kk], acc[m][n]);
        __builtin_amdgcn_s_setprio(0);
        asm volatile("" ::: "memory");
        __bf16* ta = a0; a0 = a1; a1 = a2; a2 = ta;
        __bf16* tb = b0; b0 = b1; b1 = b2; b2 = tb;
    }

    // epilogue: D layout col=lane&15, row=(lane>>4)*4+r
    #pragma unroll
    for (int m = 0; m < 8; m++) {
        #pragma unroll
        for (int n = 0; n < NFRAG; n++) {
            int Rb = row0 + wr * 128 + m * 16 + g * 4;
            int C = col0 + wc * WC + n * 16 + qi;
            if constexpr (EPI == 6) {
                int region = C >> 11;        // uniform per block (BN=128)
                int Cl = C & 2047;
                if (region < 2) {
                    __bf16* dst = (__bf16*)(region == 0 ? C0 : C1);
                    #pragma unroll
                    for (int r = 0; r < 4; r++)
                        dst[(size_t)(Rb + r) * 2048 + Cl] = (__bf16)acc[m][n][r];
                } else {
                    bf16x4 pk;
                    #pragma unroll
                    for (int r = 0; r < 4; r++) pk[r] = (__bf16)acc[m][n][r];
                    int b = Rb >> 11, t0 = Rb & 2047, hh = Cl >> 7, d = Cl & 127;
                    *(bf16x4*)((__bf16*)C2 + ((size_t)(b * NH + hh) * DH + d) * TT + t0) = pk;
                }
            } else {
                #pragma unroll
                for (int r = 0; r < 4; r++) {
                    int R = Rb + r;
                    float v = acc[m][n][r];
                    size_t idx = (size_t)R * N + C;
                    if constexpr (EPI == 0) {
                        ((__bf16*)C0)[idx] = (__bf16)v;
                    } else if constexpr (EPI == 2) {
                        ((float*)C0)[idx] = resid[idx] + v;
                    } else if constexpr (EPI == 3) {
                        float u = v + bias[C];
                        ((__bf16*)C0)[idx] = (__bf16)(u / (1.f + __expf(-u)));
                    } else if constexpr (EPI == 4) {
                        float u = v + bias[C];
                        ((float*)C0)[idx] = resid[idx] + u;
                    }
                }
            }
        }
    }
}

// ---------------- flash attention, KVBLK=64 LDS-staged + XOR swizzle --------
__global__ __launch_bounds__(256) void attn_kernel(
    const __bf16* __restrict__ qh, const __bf16* __restrict__ kh,
    const __bf16* __restrict__ vt, __bf16* __restrict__ out) {
    __shared__ __align__(16) __bf16 Ks[64 * 128];
    __shared__ __align__(16) __bf16 Vts[128 * 64];
    __shared__ __align__(16) __bf16 plds[4][1024];
    int tid = threadIdx.x;
    int w = tid >> 6, l = tid & 63;
    int qi = l & 15, g = l >> 4;
    int bh = blockIdx.y;
    int b = bh >> 4, hd = bh & 15;
    int qtile = gridDim.x - 1 - blockIdx.x;
    int qbase = qtile * 64 + w * 16;
    int qg = qbase + qi;

    const __bf16* qrow = qh + ((size_t)b * TT + qg) * HID + hd * DH;
    const __bf16* kbase = kh + (size_t)b * TT * HID + hd * DH;
    const __bf16* vtb = vt + (size_t)bh * DH * TT;

    bf16x8 bq[4];
    #pragma unroll
    for (int kc = 0; kc < 4; kc++)
        bq[kc] = *(const bf16x8*)(qrow + kc * 32 + g * 8);

    f32x4 O[8] = {};
    float m_run = -3.0e38f, l_run = 0.f;
    const float scale = 0.08838834764831845f;
    int nt = qtile + 1;

    for (int it = 0; it < nt; it++) {
        int kv0 = it * 64;
        __syncthreads();
        #pragma unroll
        for (int i = 0; i < 4; i++) {
            int j = (w * 4 + i) * 64 + l;
            int r = j >> 4, u = j & 15;
            int cb = (u * 16) ^ ((r & 7) << 4);
            gload_lds16(kbase + (size_t)(kv0 + r) * HID + (cb >> 1),
                        Ks + (w * 4 + i) * 512);
        }
        #pragma unroll
        for (int i = 0; i < 4; i++) {
            int j = (w * 4 + i) * 64 + l;
            int r = j >> 3, u = j & 7;
            int cb = (u * 16) ^ ((r & 7) << 4);
            gload_lds16(vtb + (size_t)r * TT + kv0 + (cb >> 1),
                        Vts + (w * 4 + i) * 512);
        }
        __syncthreads();

        f32x4 st[4] = {};
        __builtin_amdgcn_s_setprio(1);
        #pragma unroll
        for (int t = 0; t < 4; t++) {
            #pragma unroll
            for (int kc = 0; kc < 4; kc++) {
                int row = t * 16 + qi;
                int cb = (kc * 64 + g * 16) ^ ((qi & 7) << 4);
                bf16x8 ak = *(const bf16x8*)(Ks + row * 128 + (cb >> 1));
                st[t] = mfma16(ak, bq[kc], st[t]);
            }
        }
        __builtin_amdgcn_s_setprio(0);
        float s[16];
        #pragma unroll
        for (int t = 0; t < 4; t++)
            #pragma unroll
            for (int r = 0; r < 4; r++) s[t * 4 + r] = st[t][r] * scale;
        #pragma unroll
        for (int i = 0; i < 16; i++) {
            int kvg = kv0 + (i >> 2) * 16 + g * 4 + (i & 3);
            if (kvg > qg) s[i] = -3.0e38f;
        }
        float mt = s[0];
        #pragma unroll
        for (int i = 1; i < 16; i++) mt = fmaxf(mt, s[i]);
        mt = fmaxf(mt, __shfl_xor(mt, 16));
        mt = fmaxf(mt, __shfl_xor(mt, 32));
        float m_new = fmaxf(m_run, mt);
        float alpha = __expf(m_run - m_new);
        float p[16], ps = 0.f;
        #pragma unroll
        for (int i = 0; i < 16; i++) { p[i] = __expf(s[i] - m_new); ps += p[i]; }
        ps += __shfl_xor(ps, 16);
        ps += __shfl_xor(ps, 32);
        l_run = l_run * alpha + ps;
        m_run = m_new;

        #pragma unroll
        for (int t = 0; t < 4; t++) {
            bf16x4 pk;
            #pragma unroll
            for (int r = 0; r < 4; r++) pk[r] = (__bf16)p[t * 4 + r];
            int cb = (t * 32 + g * 8) ^ ((qi & 7) << 4);
            *(bf16x4*)(&plds[w][qi * 64 + (cb >> 1)]) = pk;
        }

        float av[4];
        #pragma unroll
        for (int r = 0; r < 4; r++) av[r] = __shfl(alpha, (g << 4) | (g * 4 + r));
        #pragma unroll
        for (int oc = 0; oc < 8; oc++)
            #pragma unroll
            for (int r = 0; r < 4; r++) O[oc][r] *= av[r];

        #pragma unroll
        for (int h = 0; h < 2; h++) {
            int cbp = (h * 64 + g * 16) ^ ((qi & 7) << 4);
            bf16x8 ap = *(const bf16x8*)(&plds[w][qi * 64 + (cbp >> 1)]);
            __builtin_amdgcn_s_setprio(1);
            #pragma unroll
            for (int oc = 0; oc < 8; oc++) {
                int row = oc * 16 + qi;
                int cb = (h * 64 + g * 16) ^ ((qi & 7) << 4);
                bf16x8 bv = *(const bf16x8*)(Vts + row * 64 + (cb >> 1));
                O[oc] = mfma16(ap, bv, O[oc]);
            }
            __builtin_amdgcn_s_setprio(0);
        }
    }

    float linv[4];
    #pragma unroll
    for (int r = 0; r < 4; r++) {
        float lq = __shfl(l_run, (g << 4) | (g * 4 + r));
        linv[r] = 1.0f / lq;
    }
    __bf16* op = out + ((size_t)b * TT + qbase) * HID + hd * DH;
    #pragma unroll
    for (int oc = 0; oc < 8; oc++)
        #pragma unroll
        for (int r = 0; r < 4; r++)
            op[(size_t)(g * 4 + r) * HID + oc * 16 + qi] = (__bf16)(O[oc][r] * linv[r]);
}

// ---------------- launch ----------------------------------------------------
extern "C" void kernel_launch(void* const* d_in, const int* in_sizes, int n_in,
                              void* d_out, int out_size, void* d_ws, size_t ws_size,
                              hipStream_t stream) {
    const float* x    = (const float*)d_in[0];
    const float* Wq   = (const float*)d_in[2];
    const float* Wk   = (const float*)d_in[3];
    const float* Wv   = (const float*)d_in[4];
    const float* Wo   = (const float*)d_in[5];
    const float* ln1w = (const float*)d_in[6];
    const float* ln1b = (const float*)d_in[7];
    const float* ln2w = (const float*)d_in[8];
    const float* ln2b = (const float*)d_in[9];
    const float* W1   = (const float*)d_in[10];
    const float* b1   = (const float*)d_in[11];
    const float* W2   = (const float*)d_in[12];
    const float* b2   = (const float*)d_in[13];
    float* outp = (float*)d_out;

    char* ws = (char*)d_ws;
    const size_t SZ_W   = (size_t)HID * HID * 2;
    const size_t SZ_WF  = (size_t)HID * DFF * 2;
    const size_t SZ_ACT = (size_t)MROWS * HID * 2;
    const size_t SZ_X32 = (size_t)MROWS * HID * 4;

    __bf16* wqT  = (__bf16*)(ws);                   // wq|wk|wv contiguous
    __bf16* wkT  = (__bf16*)(ws + SZ_W);
    __bf16* wvT  = (__bf16*)(ws + 2 * SZ_W);
    __bf16* woT  = (__bf16*)(ws + 3 * SZ_W);
    __bf16* w1T  = (__bf16*)(ws + 4 * SZ_W);
    __bf16* w2T  = (__bf16*)(ws + 4 * SZ_W + SZ_WF);
    __bf16* h    = (__bf16*)(ws + 4 * SZ_W + 2 * SZ_WF);
    float*  x1   = (float*) (ws + 4 * SZ_W + 2 * SZ_WF + SZ_ACT);
    char*   base = ws + 4 * SZ_W + 2 * SZ_WF + SZ_ACT + SZ_X32;
    __bf16* qb   = (__bf16*)(base);
    __bf16* kb   = (__bf16*)(base + SZ_ACT);
    __bf16* vtb  = (__bf16*)(base + 2 * SZ_ACT);
    __bf16* attn = (__bf16*)(base + 3 * SZ_ACT);
    __bf16* mlp1 = (__bf16*)(base);                  // aliases q/k/vt/attn

    dim3 blk256(256), blk512(512);
    transpose_bf16_kernel<HID, HID><<<dim3(32, 32), blk256, 0, stream>>>(Wq, wqT);
    transpose_bf16_kernel<HID, HID><<<dim3(32, 32), blk256, 0, stream>>>(Wk, wkT);
    transpose_bf16_kernel<HID, HID><<<dim3(32, 32), blk256, 0, stream>>>(Wv, wvT);
    transpose_bf16_kernel<HID, HID><<<dim3(32, 32), blk256, 0, stream>>>(Wo, woT);
    transpose_bf16_kernel<HID, DFF><<<dim3(128, 32), blk256, 0, stream>>>(W1, w1T);
    transpose_bf16_kernel<DFF, HID><<<dim3(32, 128), blk256, 0, stream>>>(W2, w2T);

    ln_kernel<<<MROWS, blk256, 0, stream>>>(x, ln1w, ln1b, h);

    // fused QKV: N=6144, BN=128 -> 16x48 = 768 blocks
    gemm8<6, 128, 64, 6144, HID><<<768, blk512, 0, stream>>>(
        h, wqT, qb, kb, vtb, nullptr, nullptr, 48);

    attn_kernel<<<dim3(TT / 64, BB * NH), blk256, 0, stream>>>(qb, kb, vtb, attn);

    // O projection + residual: 16x16 = 256 blocks
    gemm8<2, 128, 64, HID, HID><<<256, blk512, 0, stream>>>(
        attn, woT, x1, nullptr, nullptr, x, nullptr, 16);

    ln_kernel<<<MROWS, blk256, 0, stream>>>(x1, ln2w, ln2b, h);

    // MLP1: N=8192, BN=128 (conflict-free BK=64) -> 16x64 = 1024 blocks
    gemm8<3, 128, 64, DFF, HID><<<1024, blk512, 0, stream>>>(
        h, w1T, mlp1, nullptr, nullptr, nullptr, b1, 64);

    // MLP2: K=8192, BN=128 -> 16x16 = 256 blocks
    gemm8<4, 128, 64, HID, DFF><<<256, blk512, 0, stream>>>(
        mlp1, w2T, outp, nullptr, nullptr, x1, b2, 16);
}

// Round 10
// 773.633 us; speedup vs baseline: 1.1061x; 1.0186x over previous
//
#include <hip/hip_runtime.h>

#define HID 2048
#define NH 16
#define DH 128
#define DFF 8192
#define BB 2
#define TT 2048
#define MROWS 4096   // B*T

typedef __bf16 bf16x8 __attribute__((ext_vector_type(8)));
typedef __bf16 bf16x4 __attribute__((ext_vector_type(4)));
typedef float  f32x4  __attribute__((ext_vector_type(4)));

__device__ __forceinline__ f32x4 mfma16(bf16x8 a, bf16x8 b, f32x4 c) {
    return __builtin_amdgcn_mfma_f32_16x16x32_bf16(a, b, c, 0, 0, 0);
}

__device__ __forceinline__ void gload_lds16(const __bf16* gsrc, __bf16* ldst) {
    __builtin_amdgcn_global_load_lds(
        (const __attribute__((address_space(1))) void*)gsrc,
        (__attribute__((address_space(3))) void*)ldst, 16, 0, 0);
}

// ---------------- weight transpose+convert: W[K][N] f32 -> Wt[N][K] bf16 ----
template<int K, int N>
__global__ __launch_bounds__(256) void transpose_bf16_kernel(
    const float* __restrict__ W, __bf16* __restrict__ Wt) {
    __shared__ float tile[64][65];
    int t = threadIdx.x;
    int n0 = blockIdx.x * 64, k0 = blockIdx.y * 64;
    int n4 = (t & 15) * 4, kk = t >> 4;
    #pragma unroll
    for (int i = 0; i < 4; i++) {
        int k = i * 16 + kk;
        float4 v = *(const float4*)(W + (size_t)(k0 + k) * N + n0 + n4);
        tile[k][n4] = v.x; tile[k][n4 + 1] = v.y;
        tile[k][n4 + 2] = v.z; tile[k][n4 + 3] = v.w;
    }
    __syncthreads();
    int k4 = (t & 15) * 4, nn = t >> 4;
    #pragma unroll
    for (int i = 0; i < 4; i++) {
        int n = i * 16 + nn;
        bf16x4 o;
        #pragma unroll
        for (int j = 0; j < 4; j++) o[j] = (__bf16)tile[k4 + j][n];
        *(bf16x4*)(Wt + (size_t)(n0 + n) * K + k0 + k4) = o;
    }
}

// ---------------- LayerNorm f32 -> bf16 ------------------------------------
__global__ __launch_bounds__(256) void ln_kernel(
    const float* __restrict__ x, const float* __restrict__ gw,
    const float* __restrict__ gb, __bf16* __restrict__ out) {
    int row = blockIdx.x;
    int t = threadIdx.x;
    const float* xr = x + (size_t)row * HID;
    float4 v0 = *(const float4*)(xr + t * 8);
    float4 v1 = *(const float4*)(xr + t * 8 + 4);
    float xv[8] = {v0.x, v0.y, v0.z, v0.w, v1.x, v1.y, v1.z, v1.w};
    float s = 0.f, q = 0.f;
    #pragma unroll
    for (int j = 0; j < 8; j++) { s += xv[j]; q += xv[j] * xv[j]; }
    #pragma unroll
    for (int off = 1; off < 64; off <<= 1) {
        s += __shfl_xor(s, off);
        q += __shfl_xor(q, off);
    }
    __shared__ float ssum[4], ssq[4];
    if ((t & 63) == 0) { ssum[t >> 6] = s; ssq[t >> 6] = q; }
    __syncthreads();
    s = ssum[0] + ssum[1] + ssum[2] + ssum[3];
    q = ssq[0] + ssq[1] + ssq[2] + ssq[3];
    float mu = s * (1.0f / HID);
    float var = q * (1.0f / HID) - mu * mu;
    float rs = rsqrtf(var + 1e-5f);
    bf16x8 o;
    #pragma unroll
    for (int j = 0; j < 8; j++)
        o[j] = (__bf16)((xv[j] - mu) * rs * gw[t * 8 + j] + gb[t * 8 + j]);
    *(bf16x8*)(out + (size_t)row * HID + t * 8) = o;
}

// ---------------- 8-wave pipelined GEMM (R3 engine) -------------------------
// BM=256. 3-deep LDS rotation, counted vmcnt (never 0 mid-loop), 1 barrier
// per K-step, XOR-swizzled LDS (both sides), setprio around MFMA, XCD swizzle.
// Config per-op from measured bests: BN=256/BK=32 for K=2048 big-N GEMMs
// (QKV, MLP1); BN=128/BK=64 for N=2048 (O-proj, MLP2).
// EPI: 0=plain bf16, 2=f32 +resid, 3=bf16 silu(+bias), 4=f32 +bias+resid,
//      6=QKV split (C0=q bf16, C1=k bf16, C2=v transposed [B,NH,DH,T])
template<int EPI, int BN, int BK, int N, int K>
__global__ __launch_bounds__(512) void gemm8(
    const __bf16* __restrict__ A, const __bf16* __restrict__ Bt,
    void* __restrict__ C0, void* __restrict__ C1, void* __restrict__ C2,
    const float* __restrict__ resid, const float* __restrict__ bias, int nN) {
    constexpr int BM = 256;
    constexpr int CPR = BK / 8;                 // 16B chunks per LDS row
    constexpr int RND_A = BM * BK * 2 / 8192;   // staging rounds (512thr x 16B)
    constexpr int RND_B = BN * BK * 2 / 8192;
    constexpr int LPT = RND_A + RND_B;          // loads/thread/tile
    constexpr int NT = K / BK;
    constexpr int WC = BN / 4;                  // wave col span
    constexpr int NFRAG = WC / 16;
    constexpr int KK = BK / 32;

    __shared__ __align__(16) __bf16 As[3][BM * BK];
    __shared__ __align__(16) __bf16 Bs[3][BN * BK];

    int tid = threadIdx.x;
    int w = tid >> 6, l = tid & 63;
    int wr = w >> 2, wc = w & 3;
    int qi = l & 15, g = l >> 4;

    int nwg = gridDim.x;
    int bid = blockIdx.x;
    int wg = (bid & 7) * (nwg >> 3) + (bid >> 3);   // XCD swizzle (nwg%8==0)
    int bm = wg / nN, bn = wg % nN;
    int row0 = bm * BM, col0 = bn * BN;

    // per-thread staging source pointers (pre-swizzled chunk, rule #21)
    const __bf16* pA[RND_A];
    #pragma unroll
    for (int i = 0; i < RND_A; i++) {
        int slot = i * 512 + tid;
        int r = slot / CPR, u = slot % CPR;
        pA[i] = A + (size_t)(row0 + r) * K + (u ^ (r & (CPR - 1))) * 8;
    }
    const __bf16* pB[RND_B];
    #pragma unroll
    for (int i = 0; i < RND_B; i++) {
        int slot = i * 512 + tid;
        int r = slot / CPR, u = slot % CPR;
        pB[i] = Bt + (size_t)(col0 + r) * K + (u ^ (r & (CPR - 1))) * 8;
    }
    int wbase = w * 64 * 8;   // wave-uniform LDS dest base (elements)

    f32x4 acc[8][NFRAG] = {};

    // prologue: stage tiles 0,1
    #pragma unroll
    for (int tt = 0; tt < 2; tt++) {
        #pragma unroll
        for (int i = 0; i < RND_A; i++)
            gload_lds16(pA[i] + tt * BK, &As[tt][i * 4096 + wbase]);
        #pragma unroll
        for (int i = 0; i < RND_B; i++)
            gload_lds16(pB[i] + tt * BK, &Bs[tt][i * 4096 + wbase]);
    }

    __bf16 *a0 = As[0], *a1 = As[1], *a2 = As[2];
    __bf16 *b0 = Bs[0], *b1 = Bs[1], *b2 = Bs[2];

    for (int t = 0; t < NT; t++) {
        // tile t landed when <= LPT (tile t+1's loads) outstanding — counted
        if constexpr (LPT == 6) asm volatile("s_waitcnt vmcnt(6)" ::: "memory");
        else                    asm volatile("s_waitcnt vmcnt(4)" ::: "memory");
        __builtin_amdgcn_s_barrier();
        asm volatile("" ::: "memory");
        if (t + 2 < NT) {   // stage tile t+2 into slot that held tile t-1
            #pragma unroll
            for (int i = 0; i < RND_A; i++)
                gload_lds16(pA[i] + (t + 2) * BK, a2 + i * 4096 + wbase);
            #pragma unroll
            for (int i = 0; i < RND_B; i++)
                gload_lds16(pB[i] + (t + 2) * BK, b2 + i * 4096 + wbase);
        }
        bf16x8 af[8][KK], bfr[NFRAG][KK];
        #pragma unroll
        for (int m = 0; m < 8; m++) {
            int r = wr * 128 + m * 16 + qi;
            #pragma unroll
            for (int kk = 0; kk < KK; kk++) {
                int byt = r * (BK * 2) + ((kk * 64 + g * 16) ^ ((r & (CPR - 1)) << 4));
                af[m][kk] = *(const bf16x8*)((const char*)a0 + byt);
            }
        }
        #pragma unroll
        for (int n = 0; n < NFRAG; n++) {
            int r = wc * WC + n * 16 + qi;
            #pragma unroll
            for (int kk = 0; kk < KK; kk++) {
                int byt = r * (BK * 2) + ((kk * 64 + g * 16) ^ ((r & (CPR - 1)) << 4));
                bfr[n][kk] = *(const bf16x8*)((const char*)b0 + byt);
            }
        }
        __builtin_amdgcn_s_setprio(1);
        #pragma unroll
        for (int kk = 0; kk < KK; kk++)
            #pragma unroll
            for (int m = 0; m < 8; m++)
                #pragma unroll
                for (int n = 0; n < NFRAG; n++)
                    acc[m][n] = mfma16(af[m][kk], bfr[n][kk], acc[m][n]);
        __builtin_amdgcn_s_setprio(0);
        asm volatile("" ::: "memory");
        __bf16* ta = a0; a0 = a1; a1 = a2; a2 = ta;
        __bf16* tb = b0; b0 = b1; b1 = b2; b2 = tb;
    }

    // epilogue: D layout col=lane&15, row=(lane>>4)*4+r
    #pragma unroll
    for (int m = 0; m < 8; m++) {
        #pragma unroll
        for (int n = 0; n < NFRAG; n++) {
            int Rb = row0 + wr * 128 + m * 16 + g * 4;
            int C = col0 + wc * WC + n * 16 + qi;
            if constexpr (EPI == 6) {
                int region = C >> 11;        // uniform per block (BN | 2048)
                int Cl = C & 2047;
                if (region < 2) {
                    __bf16* dst = (__bf16*)(region == 0 ? C0 : C1);
                    #pragma unroll
                    for (int r = 0; r < 4; r++)
                        dst[(size_t)(Rb + r) * 2048 + Cl] = (__bf16)acc[m][n][r];
                } else {
                    bf16x4 pk;
                    #pragma unroll
                    for (int r = 0; r < 4; r++) pk[r] = (__bf16)acc[m][n][r];
                    int b = Rb >> 11, t0 = Rb & 2047, hh = Cl >> 7, d = Cl & 127;
                    *(bf16x4*)((__bf16*)C2 + ((size_t)(b * NH + hh) * DH + d) * TT + t0) = pk;
                }
            } else {
                #pragma unroll
                for (int r = 0; r < 4; r++) {
                    int R = Rb + r;
                    float v = acc[m][n][r];
                    size_t idx = (size_t)R * N + C;
                    if constexpr (EPI == 0) {
                        ((__bf16*)C0)[idx] = (__bf16)v;
                    } else if constexpr (EPI == 2) {
                        ((float*)C0)[idx] = resid[idx] + v;
                    } else if constexpr (EPI == 3) {
                        float u = v + bias[C];
                        ((__bf16*)C0)[idx] = (__bf16)(u / (1.f + __expf(-u)));
                    } else if constexpr (EPI == 4) {
                        float u = v + bias[C];
                        ((float*)C0)[idx] = resid[idx] + u;
                    }
                }
            }
        }
    }
}

// ---------------- flash attention, KVBLK=64 LDS-staged + XOR swizzle --------
__global__ __launch_bounds__(256) void attn_kernel(
    const __bf16* __restrict__ qh, const __bf16* __restrict__ kh,
    const __bf16* __restrict__ vt, __bf16* __restrict__ out) {
    __shared__ __align__(16) __bf16 Ks[64 * 128];
    __shared__ __align__(16) __bf16 Vts[128 * 64];
    __shared__ __align__(16) __bf16 plds[4][1024];
    int tid = threadIdx.x;
    int w = tid >> 6, l = tid & 63;
    int qi = l & 15, g = l >> 4;
    int bh = blockIdx.y;
    int b = bh >> 4, hd = bh & 15;
    int qtile = gridDim.x - 1 - blockIdx.x;
    int qbase = qtile * 64 + w * 16;
    int qg = qbase + qi;

    const __bf16* qrow = qh + ((size_t)b * TT + qg) * HID + hd * DH;
    const __bf16* kbase = kh + (size_t)b * TT * HID + hd * DH;
    const __bf16* vtb = vt + (size_t)bh * DH * TT;

    bf16x8 bq[4];
    #pragma unroll
    for (int kc = 0; kc < 4; kc++)
        bq[kc] = *(const bf16x8*)(qrow + kc * 32 + g * 8);

    f32x4 O[8] = {};
    float m_run = -3.0e38f, l_run = 0.f;
    const float scale = 0.08838834764831845f;
    int nt = qtile + 1;

    for (int it = 0; it < nt; it++) {
        int kv0 = it * 64;
        __syncthreads();
        #pragma unroll
        for (int i = 0; i < 4; i++) {
            int j = (w * 4 + i) * 64 + l;
            int r = j >> 4, u = j & 15;
            int cb = (u * 16) ^ ((r & 7) << 4);
            gload_lds16(kbase + (size_t)(kv0 + r) * HID + (cb >> 1),
                        Ks + (w * 4 + i) * 512);
        }
        #pragma unroll
        for (int i = 0; i < 4; i++) {
            int j = (w * 4 + i) * 64 + l;
            int r = j >> 3, u = j & 7;
            int cb = (u * 16) ^ ((r & 7) << 4);
            gload_lds16(vtb + (size_t)r * TT + kv0 + (cb >> 1),
                        Vts + (w * 4 + i) * 512);
        }
        __syncthreads();

        f32x4 st[4] = {};
        __builtin_amdgcn_s_setprio(1);
        #pragma unroll
        for (int t = 0; t < 4; t++) {
            #pragma unroll
            for (int kc = 0; kc < 4; kc++) {
                int row = t * 16 + qi;
                int cb = (kc * 64 + g * 16) ^ ((qi & 7) << 4);
                bf16x8 ak = *(const bf16x8*)(Ks + row * 128 + (cb >> 1));
                st[t] = mfma16(ak, bq[kc], st[t]);
            }
        }
        __builtin_amdgcn_s_setprio(0);
        float s[16];
        #pragma unroll
        for (int t = 0; t < 4; t++)
            #pragma unroll
            for (int r = 0; r < 4; r++) s[t * 4 + r] = st[t][r] * scale;
        #pragma unroll
        for (int i = 0; i < 16; i++) {
            int kvg = kv0 + (i >> 2) * 16 + g * 4 + (i & 3);
            if (kvg > qg) s[i] = -3.0e38f;
        }
        float mt = s[0];
        #pragma unroll
        for (int i = 1; i < 16; i++) mt = fmaxf(mt, s[i]);
        mt = fmaxf(mt, __shfl_xor(mt, 16));
        mt = fmaxf(mt, __shfl_xor(mt, 32));
        float m_new = fmaxf(m_run, mt);
        float alpha = __expf(m_run - m_new);
        float p[16], ps = 0.f;
        #pragma unroll
        for (int i = 0; i < 16; i++) { p[i] = __expf(s[i] - m_new); ps += p[i]; }
        ps += __shfl_xor(ps, 16);
        ps += __shfl_xor(ps, 32);
        l_run = l_run * alpha + ps;
        m_run = m_new;

        #pragma unroll
        for (int t = 0; t < 4; t++) {
            bf16x4 pk;
            #pragma unroll
            for (int r = 0; r < 4; r++) pk[r] = (__bf16)p[t * 4 + r];
            int cb = (t * 32 + g * 8) ^ ((qi & 7) << 4);
            *(bf16x4*)(&plds[w][qi * 64 + (cb >> 1)]) = pk;
        }

        float av[4];
        #pragma unroll
        for (int r = 0; r < 4; r++) av[r] = __shfl(alpha, (g << 4) | (g * 4 + r));
        #pragma unroll
        for (int oc = 0; oc < 8; oc++)
            #pragma unroll
            for (int r = 0; r < 4; r++) O[oc][r] *= av[r];

        #pragma unroll
        for (int h = 0; h < 2; h++) {
            int cbp = (h * 64 + g * 16) ^ ((qi & 7) << 4);
            bf16x8 ap = *(const bf16x8*)(&plds[w][qi * 64 + (cbp >> 1)]);
            __builtin_amdgcn_s_setprio(1);
            #pragma unroll
            for (int oc = 0; oc < 8; oc++) {
                int row = oc * 16 + qi;
                int cb = (h * 64 + g * 16) ^ ((qi & 7) << 4);
                bf16x8 bv = *(const bf16x8*)(Vts + row * 64 + (cb >> 1));
                O[oc] = mfma16(ap, bv, O[oc]);
            }
            __builtin_amdgcn_s_setprio(0);
        }
    }

    float linv[4];
    #pragma unroll
    for (int r = 0; r < 4; r++) {
        float lq = __shfl(l_run, (g << 4) | (g * 4 + r));
        linv[r] = 1.0f / lq;
    }
    __bf16* op = out + ((size_t)b * TT + qbase) * HID + hd * DH;
    #pragma unroll
    for (int oc = 0; oc < 8; oc++)
        #pragma unroll
        for (int r = 0; r < 4; r++)
            op[(size_t)(g * 4 + r) * HID + oc * 16 + qi] = (__bf16)(O[oc][r] * linv[r]);
}

// ---------------- launch ----------------------------------------------------
extern "C" void kernel_launch(void* const* d_in, const int* in_sizes, int n_in,
                              void* d_out, int out_size, void* d_ws, size_t ws_size,
                              hipStream_t stream) {
    const float* x    = (const float*)d_in[0];
    const float* Wq   = (const float*)d_in[2];
    const float* Wk   = (const float*)d_in[3];
    const float* Wv   = (const float*)d_in[4];
    const float* Wo   = (const float*)d_in[5];
    const float* ln1w = (const float*)d_in[6];
    const float* ln1b = (const float*)d_in[7];
    const float* ln2w = (const float*)d_in[8];
    const float* ln2b = (const float*)d_in[9];
    const float* W1   = (const float*)d_in[10];
    const float* b1   = (const float*)d_in[11];
    const float* W2   = (const float*)d_in[12];
    const float* b2   = (const float*)d_in[13];
    float* outp = (float*)d_out;

    char* ws = (char*)d_ws;
    const size_t SZ_W   = (size_t)HID * HID * 2;
    const size_t SZ_WF  = (size_t)HID * DFF * 2;
    const size_t SZ_ACT = (size_t)MROWS * HID * 2;
    const size_t SZ_X32 = (size_t)MROWS * HID * 4;

    __bf16* wqT  = (__bf16*)(ws);                   // wq|wk|wv contiguous
    __bf16* wkT  = (__bf16*)(ws + SZ_W);
    __bf16* wvT  = (__bf16*)(ws + 2 * SZ_W);
    __bf16* woT  = (__bf16*)(ws + 3 * SZ_W);
    __bf16* w1T  = (__bf16*)(ws + 4 * SZ_W);
    __bf16* w2T  = (__bf16*)(ws + 4 * SZ_W + SZ_WF);
    __bf16* h    = (__bf16*)(ws + 4 * SZ_W + 2 * SZ_WF);
    float*  x1   = (float*) (ws + 4 * SZ_W + 2 * SZ_WF + SZ_ACT);
    char*   base = ws + 4 * SZ_W + 2 * SZ_WF + SZ_ACT + SZ_X32;
    __bf16* qb   = (__bf16*)(base);
    __bf16* kb   = (__bf16*)(base + SZ_ACT);
    __bf16* vtb  = (__bf16*)(base + 2 * SZ_ACT);
    __bf16* attn = (__bf16*)(base + 3 * SZ_ACT);
    __bf16* mlp1 = (__bf16*)(base);                  // aliases q/k/vt/attn

    dim3 blk256(256), blk512(512);
    transpose_bf16_kernel<HID, HID><<<dim3(32, 32), blk256, 0, stream>>>(Wq, wqT);
    transpose_bf16_kernel<HID, HID><<<dim3(32, 32), blk256, 0, stream>>>(Wk, wkT);
    transpose_bf16_kernel<HID, HID><<<dim3(32, 32), blk256, 0, stream>>>(Wv, wvT);
    transpose_bf16_kernel<HID, HID><<<dim3(32, 32), blk256, 0, stream>>>(Wo, woT);
    transpose_bf16_kernel<HID, DFF><<<dim3(128, 32), blk256, 0, stream>>>(W1, w1T);
    transpose_bf16_kernel<DFF, HID><<<dim3(32, 128), blk256, 0, stream>>>(W2, w2T);

    ln_kernel<<<MROWS, blk256, 0, stream>>>(x, ln1w, ln1b, h);

    // fused QKV: N=6144, BN=256/BK=32 (best per-FLOP config) -> 16x24 = 384
    gemm8<6, 256, 32, 6144, HID><<<384, blk512, 0, stream>>>(
        h, wqT, qb, kb, vtb, nullptr, nullptr, 24);

    attn_kernel<<<dim3(TT / 64, BB * NH), blk256, 0, stream>>>(qb, kb, vtb, attn);

    // O projection + residual: BN=128/BK=64 -> 16x16 = 256 blocks
    gemm8<2, 128, 64, HID, HID><<<256, blk512, 0, stream>>>(
        attn, woT, x1, nullptr, nullptr, x, nullptr, 16);

    ln_kernel<<<MROWS, blk256, 0, stream>>>(x1, ln2w, ln2b, h);

    // MLP1: N=8192, BN=256/BK=32 (R3-proven best) -> 16x32 = 512 blocks
    gemm8<3, 256, 32, DFF, HID><<<512, blk512, 0, stream>>>(
        h, w1T, mlp1, nullptr, nullptr, nullptr, b1, 32);

    // MLP2: K=8192, BN=128/BK=64 -> 16x16 = 256 blocks
    gemm8<4, 128, 64, HID, DFF><<<256, blk512, 0, stream>>>(
        mlp1, w2T, outp, nullptr, nullptr, x1, b2, 16);
}